// Round 3
// baseline (143.714 us; speedup 1.0000x reference)
//
#include <hip/hip_runtime.h>
#include <hip/hip_cooperative_groups.h>

namespace cg = cooperative_groups;

#define NT     10
#define NBATCH 16
#define SEQ    512
#define KSTEPS 10
#define NC     16
#define CL     (SEQ / NC)   // 32 intervals per chunk

// Per chunk, per state (a,m), affine maps over the chunk:
//   g_out = A*g_in + B ; integral = C*g_in + D ; loglik = E*g_in + F
// part layout (float4): slot = b*NC+c, stride 256 float4;
//   p[t]     = {A, B, C, D}
//   p[128+t] = {E, F, 0, 0}

__device__ __forceinline__ void chunk_phase(
    const float* __restrict__ times, const int* __restrict__ types,
    const float* __restrict__ Tptr,  const float* __restrict__ mu,
    const float* __restrict__ alpha, const float* __restrict__ beta,
    float4* __restrict__ part, int blk, int t)
{
    __shared__ float s_t[CL + 1];   // s_t[i] = t[k0-1+i]  (t[-1] := 0)
    __shared__ int   s_ty[CL];

    const int b  = blk / NC;
    const int c  = blk - b * NC;
    const int k0 = c * CL;
    const float* bt  = times + b * SEQ;
    const int*   bty = types + b * SEQ;
    if (t <= CL) { const int j = k0 - 1 + t; s_t[t] = (j >= 0) ? bt[j] : 0.f; }
    if (t < CL)  s_ty[t] = bty[k0 + t];
    __syncthreads();

    const bool active = (t < NT * NT);
    const int a = t / NT;
    const int m = t - a * NT;
    float al = 0.f, be = 0.f, mum = 0.f;
    if (active) {
        al  = alpha[a * NT + m];
        be  = beta [a * NT + m];
        mum = (a == 0) ? mu[m] : 0.f;   // lane (0,m) owns the mu[ty] term
    }

    float A = 1.f, gl = 0.f, C = 0.f, D = 0.f, E = 0.f, F = 0.f;
    float tprev = s_t[0];

    #pragma unroll 8
    for (int i = 0; i < CL; ++i) {
        const float te   = s_t[i + 1];
        const float h    = (te - tprev) * (1.0f / KSTEPS);
        tprev = te;
        const float x    = be * h;
        const float e1   = __expf(-x);
        const float e10  = __expf(-10.f * x);
        const float gA   = (1.f - e10 * e1) * __builtin_amdgcn_rcpf(1.f - e1);
        const float gB   = 11.f + x * (-55.f + 192.5f * x);
        const float geom = (x > 1e-3f) ? gA : gB;
        const float coef = al * geom * h;
        C = fmaf(coef, A,  C);
        D = fmaf(coef, gl, D);
        A  *= e10;
        gl *= e10;
        const int ty = s_ty[i];
        E  = (ty == m) ? fmaf(al, A,  E) : E;            // after decay, before +1
        F  = (ty == m) ? (F + fmaf(al, gl, mum)) : F;
        gl += (ty == a) ? 1.f : 0.f;
    }
    if (c == NC - 1) {   // final interval (t_{S-1}, T], quadrature only
        const float h    = (Tptr[0] - tprev) * (1.0f / KSTEPS);
        const float x    = be * h;
        const float e1   = __expf(-x);
        const float e10  = __expf(-10.f * x);
        const float gA   = (1.f - e10 * e1) * __builtin_amdgcn_rcpf(1.f - e1);
        const float gB   = 11.f + x * (-55.f + 192.5f * x);
        const float geom = (x > 1e-3f) ? gA : gB;
        const float coef = al * geom * h;
        C = fmaf(coef, A,  C);
        D = fmaf(coef, gl, D);
    }

    float4* p = part + (size_t)blk * 256 + t;
    p[0]   = make_float4(A, gl, C, D);
    p[128] = make_float4(E, F, 0.f, 0.f);
}

__device__ __forceinline__ void combine_phase(
    const float4* __restrict__ part, const float* __restrict__ mu,
    const float* __restrict__ Tptr, float* __restrict__ out, int t)
{
    float I = 0.f, Lk = 0.f;
    float g[NBATCH];
    #pragma unroll
    for (int b = 0; b < NBATCH; ++b) g[b] = 0.f;

    #pragma unroll 4
    for (int c = 0; c < NC; ++c) {
        #pragma unroll
        for (int b = 0; b < NBATCH; ++b) {
            const float4* p = part + (size_t)(b * NC + c) * 256 + t;
            const float4 v0 = p[0];     // A, B, C, D
            const float4 v1 = p[128];   // E, F, -, -
            I    += fmaf(v0.z, g[b], v0.w);
            Lk   += fmaf(v1.x, g[b], v1.y);
            g[b]  = fmaf(v0.x, g[b], v0.y);
        }
    }

    for (int off = 32; off; off >>= 1) {
        I  += __shfl_down(I, off);
        Lk += __shfl_down(Lk, off);
    }
    __shared__ float red[4];
    const int w = t >> 6, ln = t & 63;
    if (ln == 0) { red[w * 2] = I; red[w * 2 + 1] = Lk; }
    __syncthreads();
    if (t == 0) {
        const float It0 = red[0] + red[2];
        const float Lt  = red[1] + red[3];
        float mus = 0.f;
        #pragma unroll
        for (int i = 0; i < NT; ++i) mus += mu[i];
        // constant quadrature term: B * (STEPS+1) * sum(mu) * (T/STEPS)
        const float It = It0 + (float)NBATCH * (float)(KSTEPS + 1) * mus * Tptr[0] * (1.0f / KSTEPS);
        out[0] = It - Lt;
    }
}

__global__ __launch_bounds__(128) void hawkes_fused(
    const float* __restrict__ times, const int* __restrict__ types,
    const float* __restrict__ Tptr,  const float* __restrict__ mu,
    const float* __restrict__ alpha, const float* __restrict__ beta,
    float4* __restrict__ part, float* __restrict__ out)
{
    chunk_phase(times, types, Tptr, mu, alpha, beta, part, blockIdx.x, threadIdx.x);
    __threadfence();                       // push coefficient writes to device scope
    cg::this_grid().sync();
    if (blockIdx.x == 0)
        combine_phase(part, mu, Tptr, out, threadIdx.x);
}

// ---- fallback (non-cooperative) path: identical math, two dispatches ----
__global__ __launch_bounds__(128) void hawkes_chunk_k(
    const float* __restrict__ times, const int* __restrict__ types,
    const float* __restrict__ Tptr,  const float* __restrict__ mu,
    const float* __restrict__ alpha, const float* __restrict__ beta,
    float4* __restrict__ part)
{
    chunk_phase(times, types, Tptr, mu, alpha, beta, part, blockIdx.x, threadIdx.x);
}

__global__ __launch_bounds__(128) void hawkes_combine_k(
    const float4* __restrict__ part, const float* __restrict__ mu,
    const float* __restrict__ Tptr, float* __restrict__ out)
{
    combine_phase(part, mu, Tptr, out, threadIdx.x);
}

extern "C" void kernel_launch(void* const* d_in, const int* in_sizes, int n_in,
                              void* d_out, int out_size, void* d_ws, size_t ws_size,
                              hipStream_t stream) {
    const float* times = (const float*)d_in[0];
    const int*   types = (const int*)d_in[1];
    const float* T     = (const float*)d_in[2];
    const float* mu    = (const float*)d_in[3];
    const float* alpha = (const float*)d_in[4];
    const float* beta  = (const float*)d_in[5];
    float4* part = (float4*)d_ws;          // 256 slots * 256 float4 = 1 MiB
    float*  out  = (float*)d_out;

    void* kargs[] = { (void*)&times, (void*)&types, (void*)&T, (void*)&mu,
                      (void*)&alpha, (void*)&beta, (void*)&part, (void*)&out };
    hipError_t err = hipLaunchCooperativeKernel(
        reinterpret_cast<void*>(hawkes_fused),
        dim3(NBATCH * NC), dim3(128), kargs, 0, stream);

    if (err != hipSuccess) {   // capture-mode or coop unsupported: two-kernel path
        hawkes_chunk_k<<<NBATCH * NC, 128, 0, stream>>>(times, types, T, mu, alpha, beta, part);
        hawkes_combine_k<<<1, 128, 0, stream>>>(part, mu, T, out);
    }
}

// Round 4
// 100.222 us; speedup vs baseline: 1.4340x; 1.4340x over previous
//
#include <hip/hip_runtime.h>

#define NT     10
#define NBATCH 16
#define SEQ    512
#define KSTEPS 10
#define NC     16
#define CL     (SEQ / NC)   // 32 intervals per chunk

// Per chunk, per state (a,m), affine maps over the chunk:
//   g_out = A*g_in + B ; integral = C*g_in + D ; loglik = E*g_in + F
// part layout (float4): slot = b*NC+c, stride 256 float4;
//   p[t]     = {A, B, C, D}
//   p[128+t] = {E, F, 0, 0}
// counter: one uint at part + NBATCH*NC*256 float4s.

__global__ __launch_bounds__(128) void hawkes_onepass(
    const float* __restrict__ times, const int* __restrict__ types,
    const float* __restrict__ Tptr,  const float* __restrict__ mu,
    const float* __restrict__ alpha, const float* __restrict__ beta,
    float4* __restrict__ part, unsigned* __restrict__ counter,
    float* __restrict__ out)
{
    __shared__ float s_t[CL + 1];   // s_t[i] = t[k0-1+i]  (t[-1] := 0)
    __shared__ int   s_ty[CL];
    __shared__ unsigned s_last;

    const int blk = blockIdx.x;
    const int t   = threadIdx.x;
    const int b   = blk / NC;
    const int c   = blk - b * NC;
    const int k0  = c * CL;

    const float* bt  = times + b * SEQ;
    const int*   bty = types + b * SEQ;
    if (t <= CL) { const int j = k0 - 1 + t; s_t[t] = (j >= 0) ? bt[j] : 0.f; }
    if (t < CL)  s_ty[t] = bty[k0 + t];
    __syncthreads();

    const int a = t / NT;
    const int m = t - a * NT;
    const bool active = (t < NT * NT);
    float al = 0.f, be = 0.f, mum = 0.f;
    if (active) {
        al  = alpha[a * NT + m];
        be  = beta [a * NT + m];
        mum = (a == 0) ? mu[m] : 0.f;   // lane (0,m) owns the mu[ty] term
    }

    float A = 1.f, gl = 0.f, C = 0.f, D = 0.f, E = 0.f, F = 0.f;
    float tprev = s_t[0];

    #pragma unroll 8
    for (int i = 0; i < CL; ++i) {
        const float te   = s_t[i + 1];
        const float h    = (te - tprev) * (1.0f / KSTEPS);
        tprev = te;
        const float x    = be * h;
        const float e1   = __expf(-x);
        const float e10  = __expf(-10.f * x);
        const float gA   = (1.f - e10 * e1) * __builtin_amdgcn_rcpf(1.f - e1);
        const float gB   = 11.f + x * (-55.f + 192.5f * x);
        const float geom = (x > 1e-3f) ? gA : gB;
        const float coef = al * geom * h;
        C = fmaf(coef, A,  C);
        D = fmaf(coef, gl, D);
        A  *= e10;
        gl *= e10;
        const int ty = s_ty[i];
        E  = (ty == m) ? fmaf(al, A,  E) : E;            // after decay, before +1
        F  = (ty == m) ? (F + fmaf(al, gl, mum)) : F;
        gl += (ty == a) ? 1.f : 0.f;
    }
    if (c == NC - 1) {   // final interval (t_{S-1}, T], quadrature only
        const float h    = (Tptr[0] - tprev) * (1.0f / KSTEPS);
        const float x    = be * h;
        const float e1   = __expf(-x);
        const float e10  = __expf(-10.f * x);
        const float gA   = (1.f - e10 * e1) * __builtin_amdgcn_rcpf(1.f - e1);
        const float gB   = 11.f + x * (-55.f + 192.5f * x);
        const float geom = (x > 1e-3f) ? gA : gB;
        const float coef = al * geom * h;
        C = fmaf(coef, A,  C);
        D = fmaf(coef, gl, D);
    }

    {
        float4* p = part + (size_t)blk * 256 + t;
        p[0]   = make_float4(A, gl, C, D);
        p[128] = make_float4(E, F, 0.f, 0.f);
    }

    // ---- publish, then the LAST block to arrive performs the combine ----
    __threadfence();          // release: make this thread's stores device-visible
    __syncthreads();          // all threads of block have fenced
    if (t == 0) {
        const unsigned prev = atomicAdd(counter, 1u);
        s_last = (prev == (unsigned)(gridDim.x - 1)) ? 1u : 0u;
    }
    __syncthreads();
    if (!s_last) return;

    __threadfence();          // acquire: see all other blocks' stores

    float I = 0.f, Lk = 0.f;
    float g[NBATCH];
    #pragma unroll
    for (int bb = 0; bb < NBATCH; ++bb) g[bb] = 0.f;

    #pragma unroll 4
    for (int cc = 0; cc < NC; ++cc) {
        #pragma unroll
        for (int bb = 0; bb < NBATCH; ++bb) {
            const float4* p = part + (size_t)(bb * NC + cc) * 256 + t;
            const float4 v0 = p[0];     // A, B, C, D
            const float4 v1 = p[128];   // E, F, -, -
            I     += fmaf(v0.z, g[bb], v0.w);
            Lk    += fmaf(v1.x, g[bb], v1.y);
            g[bb]  = fmaf(v0.x, g[bb], v0.y);
        }
    }

    for (int off = 32; off; off >>= 1) {
        I  += __shfl_down(I, off);
        Lk += __shfl_down(Lk, off);
    }
    __shared__ float red[4];
    const int w = t >> 6, ln = t & 63;
    if (ln == 0) { red[w * 2] = I; red[w * 2 + 1] = Lk; }
    __syncthreads();
    if (t == 0) {
        const float It0 = red[0] + red[2];
        const float Lt  = red[1] + red[3];
        float mus = 0.f;
        #pragma unroll
        for (int i = 0; i < NT; ++i) mus += mu[i];
        // constant quadrature term: B * (STEPS+1) * sum(mu) * (T/STEPS)
        const float It = It0 + (float)NBATCH * (float)(KSTEPS + 1) * mus * Tptr[0] * (1.0f / KSTEPS);
        out[0] = It - Lt;
    }
}

extern "C" void kernel_launch(void* const* d_in, const int* in_sizes, int n_in,
                              void* d_out, int out_size, void* d_ws, size_t ws_size,
                              hipStream_t stream) {
    const float* times = (const float*)d_in[0];
    const int*   types = (const int*)d_in[1];
    const float* T     = (const float*)d_in[2];
    const float* mu    = (const float*)d_in[3];
    const float* alpha = (const float*)d_in[4];
    const float* beta  = (const float*)d_in[5];

    float4*   part    = (float4*)d_ws;                       // 256 slots * 4 KiB = 1 MiB
    unsigned* counter = (unsigned*)((char*)d_ws + (size_t)NBATCH * NC * 256 * sizeof(float4));
    float*    out     = (float*)d_out;

    // zero the arrival counter (d_ws is poisoned 0xAA and never re-poisoned)
    hipMemsetAsync(counter, 0, sizeof(unsigned), stream);
    hawkes_onepass<<<NBATCH * NC, 128, 0, stream>>>(times, types, T, mu, alpha, beta,
                                                    part, counter, out);
}

// Round 5
// 11.971 us; speedup vs baseline: 12.0052x; 8.3721x over previous
//
#include <hip/hip_runtime.h>

#define NT     10
#define NBATCH 16
#define SEQ    512
#define KSTEPS 10
#define NC     16
#define CL     (SEQ / NC)   // 32 intervals per chunk

// K1 writes per (chunk, state) affine maps over the chunk:
//   g_out = A*g_in + B ; integral = C*g_in + D ; loglik = E*g_in + F
// layout: p4[(b*NC+c)*128 + t] = {A,B,C,D} ; p2[(b*NC+c)*128 + t] = {E,F}
// K1 block 0 also zeroes out[0]; K2 (16 blocks, 1/batch) folds chunks and
// atomicAdds the per-batch scalar into out[0]. Kernel boundary = visibility.

__global__ __launch_bounds__(128) void hawkes_chunk(
    const float* __restrict__ times, const int* __restrict__ types,
    const float* __restrict__ Tptr,  const float* __restrict__ mu,
    const float* __restrict__ alpha, const float* __restrict__ beta,
    float4* __restrict__ p4, float2* __restrict__ p2,
    float* __restrict__ out)
{
    __shared__ float s_t[CL + 1];   // s_t[i] = t[k0-1+i]  (t[-1] := 0)
    __shared__ int   s_ty[CL];

    const int blk = blockIdx.x;
    const int t   = threadIdx.x;
    const int b   = blk / NC;
    const int c   = blk - b * NC;
    const int k0  = c * CL;

    if (blk == 0 && t == 0) out[0] = 0.f;   // ordered before K2 by kernel boundary

    const float* bt  = times + b * SEQ;
    const int*   bty = types + b * SEQ;
    if (t <= CL) { const int j = k0 - 1 + t; s_t[t] = (j >= 0) ? bt[j] : 0.f; }
    if (t < CL)  s_ty[t] = bty[k0 + t];
    __syncthreads();

    const int a = t / NT;
    const int m = t - a * NT;
    const bool active = (t < NT * NT);
    float al = 0.f, be = 0.f, mum = 0.f;
    if (active) {
        al  = alpha[a * NT + m];
        be  = beta [a * NT + m];
        mum = (a == 0) ? mu[m] : 0.f;   // lane (0,m) owns the mu[ty] term
    }

    float A = 1.f, gl = 0.f, C = 0.f, D = 0.f, E = 0.f, F = 0.f;
    float tprev = s_t[0];

    #pragma unroll 8
    for (int i = 0; i < CL; ++i) {
        const float te   = s_t[i + 1];
        const float h    = (te - tprev) * (1.0f / KSTEPS);
        tprev = te;
        const float x    = be * h;
        const float e1   = __expf(-x);
        const float e10  = __expf(-10.f * x);
        const float gA   = (1.f - e10 * e1) * __builtin_amdgcn_rcpf(1.f - e1);
        const float gB   = 11.f + x * (-55.f + 192.5f * x);
        const float geom = (x > 1e-3f) ? gA : gB;
        const float coef = al * geom * h;
        C = fmaf(coef, A,  C);
        D = fmaf(coef, gl, D);
        A  *= e10;
        gl *= e10;
        const int ty = s_ty[i];
        E  = (ty == m) ? fmaf(al, A,  E) : E;            // after decay, before +1
        F  = (ty == m) ? (F + fmaf(al, gl, mum)) : F;
        gl += (ty == a) ? 1.f : 0.f;
    }
    if (c == NC - 1) {   // final interval (t_{S-1}, T], quadrature only
        const float h    = (Tptr[0] - tprev) * (1.0f / KSTEPS);
        const float x    = be * h;
        const float e1   = __expf(-x);
        const float e10  = __expf(-10.f * x);
        const float gA   = (1.f - e10 * e1) * __builtin_amdgcn_rcpf(1.f - e1);
        const float gB   = 11.f + x * (-55.f + 192.5f * x);
        const float geom = (x > 1e-3f) ? gA : gB;
        const float coef = al * geom * h;
        C = fmaf(coef, A,  C);
        D = fmaf(coef, gl, D);
    }

    const int slot = blk * 128 + t;
    p4[slot] = make_float4(A, gl, C, D);
    p2[slot] = make_float2(E, F);
}

__global__ __launch_bounds__(128) void hawkes_fold(
    const float4* __restrict__ p4, const float2* __restrict__ p2,
    const float* __restrict__ mu, const float* __restrict__ Tptr,
    float* __restrict__ out)
{
    const int b = blockIdx.x;
    const int t = threadIdx.x;

    float g = 0.f, I = 0.f, Lk = 0.f;
    #pragma unroll
    for (int c = 0; c < NC; ++c) {
        const int slot = (b * NC + c) * 128 + t;
        const float4 v = p4[slot];   // A, B, C, D
        const float2 w = p2[slot];   // E, F
        I  += fmaf(v.z, g, v.w);
        Lk += fmaf(w.x, g, w.y);
        g   = fmaf(v.x, g, v.y);
    }

    // per-thread scalar contribution, reduce across the block
    float S = I - Lk;
    for (int off = 32; off; off >>= 1) S += __shfl_down(S, off);

    __shared__ float red[2];
    const int w = t >> 6, ln = t & 63;
    if (ln == 0) red[w] = S;
    __syncthreads();
    if (t == 0) {
        float mus = 0.f;
        #pragma unroll
        for (int i = 0; i < NT; ++i) mus += mu[i];
        // per-batch constant quadrature term: (STEPS+1) * sum(mu) * (T/STEPS)
        const float cst = (float)(KSTEPS + 1) * mus * Tptr[0] * (1.0f / KSTEPS);
        atomicAdd(out, red[0] + red[1] + cst);
    }
}

extern "C" void kernel_launch(void* const* d_in, const int* in_sizes, int n_in,
                              void* d_out, int out_size, void* d_ws, size_t ws_size,
                              hipStream_t stream) {
    const float* times = (const float*)d_in[0];
    const int*   types = (const int*)d_in[1];
    const float* T     = (const float*)d_in[2];
    const float* mu    = (const float*)d_in[3];
    const float* alpha = (const float*)d_in[4];
    const float* beta  = (const float*)d_in[5];

    const int nslots = NBATCH * NC * 128;                 // 32768
    float4* p4 = (float4*)d_ws;                           // 512 KiB
    float2* p2 = (float2*)((char*)d_ws + (size_t)nslots * sizeof(float4));  // 256 KiB
    float*  out = (float*)d_out;

    hawkes_chunk<<<NBATCH * NC, 128, 0, stream>>>(times, types, T, mu, alpha, beta,
                                                  p4, p2, out);
    hawkes_fold<<<NBATCH, 128, 0, stream>>>(p4, p2, mu, T, out);
}